// Round 9
// baseline (40.856 us; speedup 1.0000x reference)
//
#include <hip/hip_runtime.h>

#define NN 512
#define DD 128
#define HH 256

// ---------------------------------------------------------------------------
// k0: transpose W1, W2, Wo1, Wo2 (each 256x256) into ws. 64 blocks x 256 thr.
// ---------------------------------------------------------------------------
__global__ __launch_bounds__(256) void k0_tr(const float* __restrict__ W1,
                                             const float* __restrict__ W2,
                                             const float* __restrict__ Wo1,
                                             const float* __restrict__ Wo2,
                                             float* __restrict__ wsT) {
    __shared__ float tl[64][68];
    const int b = blockIdx.x;
    const int t = threadIdx.x;
    const int m = b >> 4, tile = b & 15;
    const float* src = (m == 0) ? W1 : (m == 1) ? W2 : (m == 2) ? Wo1 : Wo2;
    float* dst = wsT + m * (HH * HH);
    const int sr0 = (tile >> 2) * 64;
    const int sc0 = (tile & 3) * 64;
    const int rr = t >> 4;
    const int cc = (t & 15) * 4;
    #pragma unroll
    for (int it = 0; it < 4; ++it) {
        const int row = rr + 16 * it;
        float4 v = *(const float4*)&src[(sr0 + row) * HH + sc0 + cc];
        tl[row][cc + 0] = v.x;
        tl[row][cc + 1] = v.y;
        tl[row][cc + 2] = v.z;
        tl[row][cc + 3] = v.w;
    }
    __syncthreads();
    #pragma unroll
    for (int it = 0; it < 4; ++it) {
        const int lc = rr + 16 * it;
        float4 o;
        o.x = tl[cc + 0][lc];
        o.y = tl[cc + 1][lc];
        o.z = tl[cc + 2][lc];
        o.w = tl[cc + 3][lc];
        *(float4*)&dst[(sc0 + lc) * HH + sr0 + cc] = o;
    }
}

// ---------------------------------------------------------------------------
// k1: pa = x@Wa^T, pbb = x@Wb^T + b1 from W1T (coalesced). 256 blk x 256 thr.
// ---------------------------------------------------------------------------
__global__ __launch_bounds__(256) void k1_papb(const float* __restrict__ x,
                                               const float* __restrict__ W1T,
                                               const float* __restrict__ b1,
                                               float* __restrict__ pa,
                                               float* __restrict__ pbb) {
    __shared__ float xs[2][DD];
    const int b = blockIdx.x;
    const int t = threadIdx.x;
    const int i0 = b * 2;
    if (t < 64) {
        const int f = t * 4;
        *(float4*)&xs[f >> 7][f & 127] = *(const float4*)&x[i0 * DD + f];
    }
    __syncthreads();
    const float* wt = W1T + t;
    const int crot = (b * 8) & 127;
    float pe0 = 0.f, po0 = 0.f, pe1 = 0.f, po1 = 0.f;
    float qe0 = 0.f, qo0 = 0.f, qe1 = 0.f, qo1 = 0.f;
    #pragma unroll 2
    for (int cc0 = 0; cc0 < 128; cc0 += 8) {
        const int c = (cc0 + crot) & 127;
        float w0 = wt[(c + 0) * HH], w1 = wt[(c + 1) * HH];
        float w2 = wt[(c + 2) * HH], w3 = wt[(c + 3) * HH];
        float w4 = wt[(c + 4) * HH], w5 = wt[(c + 5) * HH];
        float w6 = wt[(c + 6) * HH], w7 = wt[(c + 7) * HH];
        float v0 = wt[(128 + c + 0) * HH], v1 = wt[(128 + c + 1) * HH];
        float v2 = wt[(128 + c + 2) * HH], v3 = wt[(128 + c + 3) * HH];
        float v4 = wt[(128 + c + 4) * HH], v5 = wt[(128 + c + 5) * HH];
        float v6 = wt[(128 + c + 6) * HH], v7 = wt[(128 + c + 7) * HH];
        float4 x0a = *(const float4*)&xs[0][c];
        float4 x0b = *(const float4*)&xs[0][c + 4];
        float4 x1a = *(const float4*)&xs[1][c];
        float4 x1b = *(const float4*)&xs[1][c + 4];
        pe0 += w0 * x0a.x + w1 * x0a.y + w2 * x0a.z + w3 * x0a.w;
        po0 += w4 * x0b.x + w5 * x0b.y + w6 * x0b.z + w7 * x0b.w;
        pe1 += w0 * x1a.x + w1 * x1a.y + w2 * x1a.z + w3 * x1a.w;
        po1 += w4 * x1b.x + w5 * x1b.y + w6 * x1b.z + w7 * x1b.w;
        qe0 += v0 * x0a.x + v1 * x0a.y + v2 * x0a.z + v3 * x0a.w;
        qo0 += v4 * x0b.x + v5 * x0b.y + v6 * x0b.z + v7 * x0b.w;
        qe1 += v0 * x1a.x + v1 * x1a.y + v2 * x1a.z + v3 * x1a.w;
        qo1 += v4 * x1b.x + v5 * x1b.y + v6 * x1b.z + v7 * x1b.w;
    }
    const float bb = b1[t];
    pa[i0 * HH + t] = pe0 + po0;
    pa[(i0 + 1) * HH + t] = pe1 + po1;
    pbb[i0 * HH + t] = qe0 + qo0 + bb;
    pbb[(i0 + 1) * HH + t] = qe1 + qo1 + bb;
}

// ---------------------------------------------------------------------------
// k2: 128 blocks x 1024 threads, 4 rows/block (halves duplicated L2 traffic).
// ---------------------------------------------------------------------------
__device__ __forceinline__ void sdot4(const float* __restrict__ wt,
                                      const float* in0, const float* in1,
                                      const float* in2, const float* in3,
                                      int hrot, float& A0, float& A1,
                                      float& A2, float& A3) {
    float a0 = 0.f, a1 = 0.f, a2 = 0.f, a3 = 0.f;
    #pragma unroll 2
    for (int hh0 = 0; hh0 < 64; hh0 += 8) {
        const int hh = (hh0 + hrot) & 63;
        float w0 = wt[(hh + 0) * HH], w1 = wt[(hh + 1) * HH];
        float w2 = wt[(hh + 2) * HH], w3 = wt[(hh + 3) * HH];
        float w4 = wt[(hh + 4) * HH], w5 = wt[(hh + 5) * HH];
        float w6 = wt[(hh + 6) * HH], w7 = wt[(hh + 7) * HH];
        float4 tA, tB;
        tA = *(const float4*)&in0[hh];
        tB = *(const float4*)&in0[hh + 4];
        a0 += w0 * tA.x + w1 * tA.y + w2 * tA.z + w3 * tA.w
            + w4 * tB.x + w5 * tB.y + w6 * tB.z + w7 * tB.w;
        tA = *(const float4*)&in1[hh];
        tB = *(const float4*)&in1[hh + 4];
        a1 += w0 * tA.x + w1 * tA.y + w2 * tA.z + w3 * tA.w
            + w4 * tB.x + w5 * tB.y + w6 * tB.z + w7 * tB.w;
        tA = *(const float4*)&in2[hh];
        tB = *(const float4*)&in2[hh + 4];
        a2 += w0 * tA.x + w1 * tA.y + w2 * tA.z + w3 * tA.w
            + w4 * tB.x + w5 * tB.y + w6 * tB.z + w7 * tB.w;
        tA = *(const float4*)&in3[hh];
        tB = *(const float4*)&in3[hh + 4];
        a3 += w0 * tA.x + w1 * tA.y + w2 * tA.z + w3 * tA.w
            + w4 * tB.x + w5 * tB.y + w6 * tB.z + w7 * tB.w;
    }
    A0 = a0; A1 = a1; A2 = a2; A3 = a3;
}

__global__ __launch_bounds__(1024) void k2_rest(const float* __restrict__ adj,
                                                const float* __restrict__ pa,
                                                const float* __restrict__ pbb,
                                                const float* __restrict__ wsT,
                                                const float* __restrict__ b2,
                                                const float* __restrict__ bo1,
                                                const float* __restrict__ bo2,
                                                float* __restrict__ out) {
    __shared__ float adjs[4][NN];        // 8 KB
    __shared__ float pbbs[4][HH];        // 4 KB
    __shared__ float ts[4][HH];          // 4 KB
    __shared__ float buf1[4][HH];        // 4 KB
    __shared__ float buf2[4][HH];        // 4 KB
    __shared__ float redbuf[4096];       // 16 KB
    __shared__ float rsum_s[4];

    const int b = blockIdx.x;
    const int t = threadIdx.x;
    const int i0 = b * 4;

    if (t < 512) {
        const int f = t * 4;
        *(float4*)&adjs[f >> 9][f & 511] = *(const float4*)&adj[(i0 + (f >> 9)) * NN + (f & 511)];
    } else if (t < 768) {
        const int f = (t - 512) * 4;
        *(float4*)&pbbs[f >> 8][f & 255] = *(const float4*)&pbb[(i0 + (f >> 8)) * HH + (f & 255)];
    }
    __syncthreads();

    if (t < 256) {
        const int r = t >> 6, l = t & 63;
        float s = 0.f;
        #pragma unroll
        for (int m = 0; m < 8; ++m) s += adjs[r][l + 64 * m];
        #pragma unroll
        for (int off = 32; off > 0; off >>= 1) s += __shfl_down(s, off, 64);
        if (l == 0) rsum_s[r] = s;
    }

    // ---- T phase: hb = t>>9, jq = (t>>7)&3, hl = t&127; 4 rows ----
    {
        const int hb = t >> 9;
        const int jq = (t >> 7) & 3;
        const int hl = t & 127;
        const int h = hb * 128 + hl;
        const float pbv0 = pbbs[0][h];
        const float pbv1 = pbbs[1][h];
        const float pbv2 = pbbs[2][h];
        const float pbv3 = pbbs[3][h];
        const float* pac = pa + (jq * 128) * HH + h;
        const int jrot = (b * 8) & 127;
        float ac0 = 0.f, ac1 = 0.f, ac2 = 0.f, ac3 = 0.f;
        #pragma unroll 2
        for (int jj0 = 0; jj0 < 128; jj0 += 8) {
            const int j = (jj0 + jrot) & 127;
            float p0 = pac[(j + 0) * HH], p1 = pac[(j + 1) * HH];
            float p2 = pac[(j + 2) * HH], p3 = pac[(j + 3) * HH];
            float p4 = pac[(j + 4) * HH], p5 = pac[(j + 5) * HH];
            float p6 = pac[(j + 6) * HH], p7 = pac[(j + 7) * HH];
            float4 Aa, Ab;
            {
                Aa = *(const float4*)&adjs[0][jq * 128 + j];
                Ab = *(const float4*)&adjs[0][jq * 128 + j + 4];
                float q0 = fmaxf(p0 + pbv0, 0.f), q1 = fmaxf(p1 + pbv0, 0.f);
                float q2 = fmaxf(p2 + pbv0, 0.f), q3 = fmaxf(p3 + pbv0, 0.f);
                float q4 = fmaxf(p4 + pbv0, 0.f), q5 = fmaxf(p5 + pbv0, 0.f);
                float q6 = fmaxf(p6 + pbv0, 0.f), q7 = fmaxf(p7 + pbv0, 0.f);
                ac0 += Aa.x * q0 + Aa.y * q1 + Aa.z * q2 + Aa.w * q3
                     + Ab.x * q4 + Ab.y * q5 + Ab.z * q6 + Ab.w * q7;
            }
            {
                Aa = *(const float4*)&adjs[1][jq * 128 + j];
                Ab = *(const float4*)&adjs[1][jq * 128 + j + 4];
                float q0 = fmaxf(p0 + pbv1, 0.f), q1 = fmaxf(p1 + pbv1, 0.f);
                float q2 = fmaxf(p2 + pbv1, 0.f), q3 = fmaxf(p3 + pbv1, 0.f);
                float q4 = fmaxf(p4 + pbv1, 0.f), q5 = fmaxf(p5 + pbv1, 0.f);
                float q6 = fmaxf(p6 + pbv1, 0.f), q7 = fmaxf(p7 + pbv1, 0.f);
                ac1 += Aa.x * q0 + Aa.y * q1 + Aa.z * q2 + Aa.w * q3
                     + Ab.x * q4 + Ab.y * q5 + Ab.z * q6 + Ab.w * q7;
            }
            {
                Aa = *(const float4*)&adjs[2][jq * 128 + j];
                Ab = *(const float4*)&adjs[2][jq * 128 + j + 4];
                float q0 = fmaxf(p0 + pbv2, 0.f), q1 = fmaxf(p1 + pbv2, 0.f);
                float q2 = fmaxf(p2 + pbv2, 0.f), q3 = fmaxf(p3 + pbv2, 0.f);
                float q4 = fmaxf(p4 + pbv2, 0.f), q5 = fmaxf(p5 + pbv2, 0.f);
                float q6 = fmaxf(p6 + pbv2, 0.f), q7 = fmaxf(p7 + pbv2, 0.f);
                ac2 += Aa.x * q0 + Aa.y * q1 + Aa.z * q2 + Aa.w * q3
                     + Ab.x * q4 + Ab.y * q5 + Ab.z * q6 + Ab.w * q7;
            }
            {
                Aa = *(const float4*)&adjs[3][jq * 128 + j];
                Ab = *(const float4*)&adjs[3][jq * 128 + j + 4];
                float q0 = fmaxf(p0 + pbv3, 0.f), q1 = fmaxf(p1 + pbv3, 0.f);
                float q2 = fmaxf(p2 + pbv3, 0.f), q3 = fmaxf(p3 + pbv3, 0.f);
                float q4 = fmaxf(p4 + pbv3, 0.f), q5 = fmaxf(p5 + pbv3, 0.f);
                float q6 = fmaxf(p6 + pbv3, 0.f), q7 = fmaxf(p7 + pbv3, 0.f);
                ac3 += Aa.x * q0 + Aa.y * q1 + Aa.z * q2 + Aa.w * q3
                     + Ab.x * q4 + Ab.y * q5 + Ab.z * q6 + Ab.w * q7;
            }
        }
        if (jq) {
            const int base = ((jq - 1) * 2 + hb) * 512;
            redbuf[base + 0 * 128 + hl] = ac0;
            redbuf[base + 1 * 128 + hl] = ac1;
            redbuf[base + 2 * 128 + hl] = ac2;
            redbuf[base + 3 * 128 + hl] = ac3;
        }
        __syncthreads();
        if (jq == 0) {
            float s0 = ac0, s1 = ac1, s2 = ac2, s3 = ac3;
            #pragma unroll
            for (int q = 1; q < 4; ++q) {
                const int base = ((q - 1) * 2 + hb) * 512;
                s0 += redbuf[base + 0 * 128 + hl];
                s1 += redbuf[base + 1 * 128 + hl];
                s2 += redbuf[base + 2 * 128 + hl];
                s3 += redbuf[base + 3 * 128 + hl];
            }
            ts[0][h] = s0;
            ts[1][h] = s1;
            ts[2][h] = s2;
            ts[3][h] = s3;
        }
    }
    __syncthreads();

    const int k = t & 255;
    const int hp = t >> 8;
    const int hrot = (b * 8) & 63;
    const float* W2T  = wsT + 1 * (HH * HH);
    const float* Wo1T = wsT + 2 * (HH * HH);
    const float* Wo2T = wsT + 3 * (HH * HH);

    // stage 1: pred = (ts @ W2T + b2*rowsum)/N -> buf1
    {
        float a0, a1, a2, a3;
        sdot4(W2T + (hp * 64) * HH + k, &ts[0][hp * 64], &ts[1][hp * 64],
              &ts[2][hp * 64], &ts[3][hp * 64], hrot, a0, a1, a2, a3);
        const int base = (hp * 4) * 256 + k;
        redbuf[base + 0 * 256] = a0;
        redbuf[base + 1 * 256] = a1;
        redbuf[base + 2 * 256] = a2;
        redbuf[base + 3 * 256] = a3;
        __syncthreads();
        if (hp == 0) {
            const float bv = b2[k];
            const float inv = 1.0f / (float)NN;
            float s0 = a0, s1 = a1, s2 = a2, s3 = a3;
            #pragma unroll
            for (int p = 1; p < 4; ++p) {
                const int pb = (p * 4) * 256 + k;
                s0 += redbuf[pb + 0 * 256];
                s1 += redbuf[pb + 1 * 256];
                s2 += redbuf[pb + 2 * 256];
                s3 += redbuf[pb + 3 * 256];
            }
            buf1[0][k] = (s0 + bv * rsum_s[0]) * inv;
            buf1[1][k] = (s1 + bv * rsum_s[1]) * inv;
            buf1[2][k] = (s2 + bv * rsum_s[2]) * inv;
            buf1[3][k] = (s3 + bv * rsum_s[3]) * inv;
        }
    }
    __syncthreads();

    // stage 2: h2 = relu(pred @ Wo1T + bo1) -> buf2
    {
        float a0, a1, a2, a3;
        sdot4(Wo1T + (hp * 64) * HH + k, &buf1[0][hp * 64], &buf1[1][hp * 64],
              &buf1[2][hp * 64], &buf1[3][hp * 64], hrot, a0, a1, a2, a3);
        const int base = (hp * 4) * 256 + k;
        redbuf[base + 0 * 256] = a0;
        redbuf[base + 1 * 256] = a1;
        redbuf[base + 2 * 256] = a2;
        redbuf[base + 3 * 256] = a3;
        __syncthreads();
        if (hp == 0) {
            const float bv = bo1[k];
            float s0 = a0, s1 = a1, s2 = a2, s3 = a3;
            #pragma unroll
            for (int p = 1; p < 4; ++p) {
                const int pb = (p * 4) * 256 + k;
                s0 += redbuf[pb + 0 * 256];
                s1 += redbuf[pb + 1 * 256];
                s2 += redbuf[pb + 2 * 256];
                s3 += redbuf[pb + 3 * 256];
            }
            buf2[0][k] = fmaxf(s0 + bv, 0.f);
            buf2[1][k] = fmaxf(s1 + bv, 0.f);
            buf2[2][k] = fmaxf(s2 + bv, 0.f);
            buf2[3][k] = fmaxf(s3 + bv, 0.f);
        }
    }
    __syncthreads();

    // stage 3: out = h2 @ Wo2T + bo2
    {
        float a0, a1, a2, a3;
        sdot4(Wo2T + (hp * 64) * HH + k, &buf2[0][hp * 64], &buf2[1][hp * 64],
              &buf2[2][hp * 64], &buf2[3][hp * 64], hrot, a0, a1, a2, a3);
        const int base = (hp * 4) * 256 + k;
        redbuf[base + 0 * 256] = a0;
        redbuf[base + 1 * 256] = a1;
        redbuf[base + 2 * 256] = a2;
        redbuf[base + 3 * 256] = a3;
        __syncthreads();
        if (hp == 0) {
            const float bv = bo2[k];
            float s0 = a0, s1 = a1, s2 = a2, s3 = a3;
            #pragma unroll
            for (int p = 1; p < 4; ++p) {
                const int pb = (p * 4) * 256 + k;
                s0 += redbuf[pb + 0 * 256];
                s1 += redbuf[pb + 1 * 256];
                s2 += redbuf[pb + 2 * 256];
                s3 += redbuf[pb + 3 * 256];
            }
            out[(i0 + 0) * HH + k] = s0 + bv;
            out[(i0 + 1) * HH + k] = s1 + bv;
            out[(i0 + 2) * HH + k] = s2 + bv;
            out[(i0 + 3) * HH + k] = s3 + bv;
        }
    }
}

extern "C" void kernel_launch(void* const* d_in, const int* in_sizes, int n_in,
                              void* d_out, int out_size, void* d_ws, size_t ws_size,
                              hipStream_t stream) {
    const float* x   = (const float*)d_in[0];
    const float* adj = (const float*)d_in[1];
    const float* W1  = (const float*)d_in[2];
    const float* b1  = (const float*)d_in[3];
    const float* W2  = (const float*)d_in[4];
    const float* b2  = (const float*)d_in[5];
    const float* Wo1 = (const float*)d_in[6];
    const float* bo1 = (const float*)d_in[7];
    const float* Wo2 = (const float*)d_in[8];
    const float* bo2 = (const float*)d_in[9];
    float* out = (float*)d_out;
    float* ws  = (float*)d_ws;

    float* wsT = ws;            // 4 * 65536: W1T, W2T, Wo1T, Wo2T
    float* pa  = ws + 262144;   // 131072
    float* pbb = ws + 393216;   // 131072

    k0_tr<<<64, 256, 0, stream>>>(W1, W2, Wo1, Wo2, wsT);
    k1_papb<<<256, 256, 0, stream>>>(x, wsT, b1, pa, pbb);
    k2_rest<<<128, 1024, 0, stream>>>(adj, pa, pbb, wsT, b2, bo1, bo2, out);
}

// Round 10
// 36.287 us; speedup vs baseline: 1.1259x; 1.1259x over previous
//
#include <hip/hip_runtime.h>

#define NN 512
#define DD 128
#define HH 256

__device__ __forceinline__ float dot4(float4 a, float4 b) {
    return a.x * b.x + a.y * b.y + a.z * b.z + a.w * b.w;
}

// ---------------------------------------------------------------------------
// kA: blocks 0..255  : pa = x@Wa^T, pbb = x@Wb^T + b1 (direct W1-row gather,
//                      L1-cached: wave's 64 rows x 256B = 16KB live set)
//     blocks 256..303: transpose W2/Wo1/Wo2 -> wsT (consumed only by kB)
// ---------------------------------------------------------------------------
__global__ __launch_bounds__(256) void kA(const float* __restrict__ x,
                                          const float* __restrict__ W1,
                                          const float* __restrict__ b1,
                                          const float* __restrict__ W2,
                                          const float* __restrict__ Wo1,
                                          const float* __restrict__ Wo2,
                                          float* __restrict__ pa,
                                          float* __restrict__ pbb,
                                          float* __restrict__ wsT) {
    __shared__ float smem[64 * 68];
    const int b = blockIdx.x;
    const int t = threadIdx.x;
    if (b < 256) {
        float (*xs)[DD] = (float(*)[DD])smem;
        const int i0 = b * 2;
        if (t < 64) {
            const int f = t * 4;
            *(float4*)&xs[f >> 7][f & 127] = *(const float4*)&x[i0 * DD + f];
        }
        __syncthreads();
        const int h = t;
        const float4* w4 = (const float4*)(W1 + h * (2 * DD));
        const float4* x0 = (const float4*)&xs[0][0];
        const float4* x1 = (const float4*)&xs[1][0];
        float a0 = 0.f, a1 = 0.f, c0 = 0.f, c1 = 0.f;
        #pragma unroll 8
        for (int d4 = 0; d4 < DD / 4; ++d4) {
            float4 wa = w4[d4];
            float4 wb = w4[d4 + 32];
            float4 v0 = x0[d4];
            float4 v1 = x1[d4];
            a0 += dot4(wa, v0);
            a1 += dot4(wa, v1);
            c0 += dot4(wb, v0);
            c1 += dot4(wb, v1);
        }
        const float bb = b1[h];
        pa[i0 * HH + h] = a0;
        pa[(i0 + 1) * HH + h] = a1;
        pbb[i0 * HH + h] = c0 + bb;
        pbb[(i0 + 1) * HH + h] = c1 + bb;
    } else {
        float (*tl)[68] = (float(*)[68])smem;
        const int bb = b - 256;
        const int m = bb >> 4, tile = bb & 15;
        const float* src = (m == 0) ? W2 : (m == 1) ? Wo1 : Wo2;
        float* dst = wsT + m * (HH * HH);
        const int sr0 = (tile >> 2) * 64;
        const int sc0 = (tile & 3) * 64;
        const int rr = t >> 4;
        const int cc = (t & 15) * 4;
        #pragma unroll
        for (int it = 0; it < 4; ++it) {
            const int row = rr + 16 * it;
            float4 v = *(const float4*)&src[(sr0 + row) * HH + sc0 + cc];
            tl[row][cc + 0] = v.x;
            tl[row][cc + 1] = v.y;
            tl[row][cc + 2] = v.z;
            tl[row][cc + 3] = v.w;
        }
        __syncthreads();
        #pragma unroll
        for (int it = 0; it < 4; ++it) {
            const int lc = rr + 16 * it;
            float4 o;
            o.x = tl[cc + 0][lc];
            o.y = tl[cc + 1][lc];
            o.z = tl[cc + 2][lc];
            o.w = tl[cc + 3][lc];
            *(float4*)&dst[(sc0 + lc) * HH + sr0 + cc] = o;
        }
    }
}

// ---------------------------------------------------------------------------
// kB: T + rowsum + 3 stage GEMMs. 256 blocks x 1024 threads, 2 rows/block.
// All reduces parallelized across 2 row-groups.
// ---------------------------------------------------------------------------
__device__ __forceinline__ void sdot2(const float* __restrict__ wt,
                                      const float* in0, const float* in1,
                                      float& A0, float& A1) {
    float e0 = 0.f, o0 = 0.f, e1 = 0.f, o1 = 0.f;
    #pragma unroll 2
    for (int hh = 0; hh < 64; hh += 8) {
        float w0 = wt[(hh + 0) * HH], w1 = wt[(hh + 1) * HH];
        float w2 = wt[(hh + 2) * HH], w3 = wt[(hh + 3) * HH];
        float w4 = wt[(hh + 4) * HH], w5 = wt[(hh + 5) * HH];
        float w6 = wt[(hh + 6) * HH], w7 = wt[(hh + 7) * HH];
        float4 t0a = *(const float4*)&in0[hh];
        float4 t0b = *(const float4*)&in0[hh + 4];
        float4 t1a = *(const float4*)&in1[hh];
        float4 t1b = *(const float4*)&in1[hh + 4];
        e0 += w0 * t0a.x + w1 * t0a.y + w2 * t0a.z + w3 * t0a.w;
        o0 += w4 * t0b.x + w5 * t0b.y + w6 * t0b.z + w7 * t0b.w;
        e1 += w0 * t1a.x + w1 * t1a.y + w2 * t1a.z + w3 * t1a.w;
        o1 += w4 * t1b.x + w5 * t1b.y + w6 * t1b.z + w7 * t1b.w;
    }
    A0 = e0 + o0;
    A1 = e1 + o1;
}

__global__ __launch_bounds__(1024) void kB(const float* __restrict__ adj,
                                           const float* __restrict__ pa,
                                           const float* __restrict__ pbb,
                                           const float* __restrict__ wsT,
                                           const float* __restrict__ b2,
                                           const float* __restrict__ bo1,
                                           const float* __restrict__ bo2,
                                           float* __restrict__ out) {
    __shared__ float adjs[2][NN];
    __shared__ float pbbs[2][HH];
    __shared__ float ts[2][HH];
    __shared__ float buf1[2][HH];
    __shared__ float buf2[2][HH];
    __shared__ float redbuf[2048];
    __shared__ float rsum_s[2];

    const int b = blockIdx.x;
    const int t = threadIdx.x;
    const int i0 = b * 2;

    if (t < 256) {
        const int f = t * 4;
        *(float4*)&adjs[f >> 9][f & 511] = *(const float4*)&adj[(i0 + (f >> 9)) * NN + (f & 511)];
    } else if (t < 384) {
        const int f = (t - 256) * 4;
        *(float4*)&pbbs[f >> 8][f & 255] = *(const float4*)&pbb[(i0 + (f >> 8)) * HH + (f & 255)];
    }
    __syncthreads();

    if (t < 128) {
        const int r = t >> 6, l = t & 63;
        float s = 0.f;
        #pragma unroll
        for (int m = 0; m < 8; ++m) s += adjs[r][l + 64 * m];
        #pragma unroll
        for (int off = 32; off > 0; off >>= 1) s += __shfl_down(s, off, 64);
        if (l == 0) rsum_s[r] = s;
    }

    // ---- T phase: hb = t>>9, jq = (t>>7)&3, hl = t&127 ----
    {
        const int hb = t >> 9;
        const int jq = (t >> 7) & 3;
        const int hl = t & 127;
        const int h = hb * 128 + hl;
        const float pb0 = pbbs[0][h];
        const float pb1 = pbbs[1][h];
        const float* pac = pa + (jq * 128) * HH + h;
        const float* arow0 = &adjs[0][jq * 128];
        const float* arow1 = &adjs[1][jq * 128];
        float ae0 = 0.f, ao0 = 0.f, ae1 = 0.f, ao1 = 0.f;
        #pragma unroll 2
        for (int j = 0; j < 128; j += 8) {
            float p0 = pac[(j + 0) * HH], p1 = pac[(j + 1) * HH];
            float p2 = pac[(j + 2) * HH], p3 = pac[(j + 3) * HH];
            float p4 = pac[(j + 4) * HH], p5 = pac[(j + 5) * HH];
            float p6 = pac[(j + 6) * HH], p7 = pac[(j + 7) * HH];
            float4 A0a = *(const float4*)&arow0[j];
            float4 A0b = *(const float4*)&arow0[j + 4];
            float4 A1a = *(const float4*)&arow1[j];
            float4 A1b = *(const float4*)&arow1[j + 4];
            float r0 = fmaxf(p0 + pb0, 0.f), r1 = fmaxf(p1 + pb0, 0.f);
            float r2 = fmaxf(p2 + pb0, 0.f), r3 = fmaxf(p3 + pb0, 0.f);
            float r4 = fmaxf(p4 + pb0, 0.f), r5 = fmaxf(p5 + pb0, 0.f);
            float r6 = fmaxf(p6 + pb0, 0.f), r7 = fmaxf(p7 + pb0, 0.f);
            ae0 += A0a.x * r0 + A0a.y * r1 + A0a.z * r2 + A0a.w * r3;
            ao0 += A0b.x * r4 + A0b.y * r5 + A0b.z * r6 + A0b.w * r7;
            float s0 = fmaxf(p0 + pb1, 0.f), s1 = fmaxf(p1 + pb1, 0.f);
            float s2 = fmaxf(p2 + pb1, 0.f), s3 = fmaxf(p3 + pb1, 0.f);
            float s4 = fmaxf(p4 + pb1, 0.f), s5 = fmaxf(p5 + pb1, 0.f);
            float s6 = fmaxf(p6 + pb1, 0.f), s7 = fmaxf(p7 + pb1, 0.f);
            ae1 += A1a.x * s0 + A1a.y * s1 + A1a.z * s2 + A1a.w * s3;
            ao1 += A1b.x * s4 + A1b.y * s5 + A1b.z * s6 + A1b.w * s7;
        }
        redbuf[((jq * 2 + hb) * 2 + 0) * 128 + hl] = ae0 + ao0;
        redbuf[((jq * 2 + hb) * 2 + 1) * 128 + hl] = ae1 + ao1;
        __syncthreads();
        if (jq < 2) {
            const int r = jq;
            float s = 0.f;
            #pragma unroll
            for (int q = 0; q < 4; ++q)
                s += redbuf[((q * 2 + hb) * 2 + r) * 128 + hl];
            ts[r][h] = s;
        }
    }
    __syncthreads();

    const int k = t & 255;
    const int hp = t >> 8;
    const float* W2T  = wsT;
    const float* Wo1T = wsT + HH * HH;
    const float* Wo2T = wsT + 2 * HH * HH;

    // stage 1: pred = (ts @ W2T + b2*rowsum)/N -> buf1
    {
        float a0, a1;
        sdot2(W2T + (hp * 64) * HH + k, &ts[0][hp * 64], &ts[1][hp * 64], a0, a1);
        redbuf[(hp * 2 + 0) * 256 + k] = a0;
        redbuf[(hp * 2 + 1) * 256 + k] = a1;
        __syncthreads();
        if (hp < 2) {
            const int r = hp;
            float s = 0.f;
            #pragma unroll
            for (int p = 0; p < 4; ++p) s += redbuf[(p * 2 + r) * 256 + k];
            buf1[r][k] = (s + b2[k] * rsum_s[r]) * (1.0f / (float)NN);
        }
    }
    __syncthreads();

    // stage 2: h2 = relu(pred @ Wo1T + bo1) -> buf2
    {
        float a0, a1;
        sdot2(Wo1T + (hp * 64) * HH + k, &buf1[0][hp * 64], &buf1[1][hp * 64], a0, a1);
        redbuf[(hp * 2 + 0) * 256 + k] = a0;
        redbuf[(hp * 2 + 1) * 256 + k] = a1;
        __syncthreads();
        if (hp < 2) {
            const int r = hp;
            float s = 0.f;
            #pragma unroll
            for (int p = 0; p < 4; ++p) s += redbuf[(p * 2 + r) * 256 + k];
            buf2[r][k] = fmaxf(s + bo1[k], 0.f);
        }
    }
    __syncthreads();

    // stage 3: out = h2 @ Wo2T + bo2
    {
        float a0, a1;
        sdot2(Wo2T + (hp * 64) * HH + k, &buf2[0][hp * 64], &buf2[1][hp * 64], a0, a1);
        redbuf[(hp * 2 + 0) * 256 + k] = a0;
        redbuf[(hp * 2 + 1) * 256 + k] = a1;
        __syncthreads();
        if (hp < 2) {
            const int r = hp;
            float s = 0.f;
            #pragma unroll
            for (int p = 0; p < 4; ++p) s += redbuf[(p * 2 + r) * 256 + k];
            out[(i0 + r) * HH + k] = s + bo2[k];
        }
    }
}

extern "C" void kernel_launch(void* const* d_in, const int* in_sizes, int n_in,
                              void* d_out, int out_size, void* d_ws, size_t ws_size,
                              hipStream_t stream) {
    const float* x   = (const float*)d_in[0];
    const float* adj = (const float*)d_in[1];
    const float* W1  = (const float*)d_in[2];
    const float* b1  = (const float*)d_in[3];
    const float* W2  = (const float*)d_in[4];
    const float* b2  = (const float*)d_in[5];
    const float* Wo1 = (const float*)d_in[6];
    const float* bo1 = (const float*)d_in[7];
    const float* Wo2 = (const float*)d_in[8];
    const float* bo2 = (const float*)d_in[9];
    float* out = (float*)d_out;
    float* ws  = (float*)d_ws;

    float* wsT = ws;            // 3 * 65536: W2T, Wo1T, Wo2T
    float* pa  = ws + 196608;   // 131072
    float* pbb = ws + 327680;   // 131072

    kA<<<304, 256, 0, stream>>>(x, W1, b1, W2, Wo1, Wo2, pa, pbb, wsT);
    kB<<<256, 1024, 0, stream>>>(adj, pa, pbb, wsT, b2, bo1, bo2, out);
}

// Round 11
// 32.812 us; speedup vs baseline: 1.2452x; 1.1059x over previous
//
#include <hip/hip_runtime.h>

#define NN 512
#define DD 128
#define HH 256

// ---------------------------------------------------------------------------
// k0: transpose W1, W2, Wo1, Wo2 (each 256x256) into ws. 64 blocks x 256 thr.
// ---------------------------------------------------------------------------
__global__ __launch_bounds__(256) void k0_tr(const float* __restrict__ W1,
                                             const float* __restrict__ W2,
                                             const float* __restrict__ Wo1,
                                             const float* __restrict__ Wo2,
                                             float* __restrict__ wsT) {
    __shared__ float tl[64][68];
    const int b = blockIdx.x;
    const int t = threadIdx.x;
    const int m = b >> 4, tile = b & 15;
    const float* src = (m == 0) ? W1 : (m == 1) ? W2 : (m == 2) ? Wo1 : Wo2;
    float* dst = wsT + m * (HH * HH);
    const int sr0 = (tile >> 2) * 64;
    const int sc0 = (tile & 3) * 64;
    const int rr = t >> 4;
    const int cc = (t & 15) * 4;
    #pragma unroll
    for (int it = 0; it < 4; ++it) {
        const int row = rr + 16 * it;
        float4 v = *(const float4*)&src[(sr0 + row) * HH + sc0 + cc];
        tl[row][cc + 0] = v.x;
        tl[row][cc + 1] = v.y;
        tl[row][cc + 2] = v.z;
        tl[row][cc + 3] = v.w;
    }
    __syncthreads();
    #pragma unroll
    for (int it = 0; it < 4; ++it) {
        const int lc = rr + 16 * it;
        float4 o;
        o.x = tl[cc + 0][lc];
        o.y = tl[cc + 1][lc];
        o.z = tl[cc + 2][lc];
        o.w = tl[cc + 3][lc];
        *(float4*)&dst[(sc0 + lc) * HH + sr0 + cc] = o;
    }
}

// ---------------------------------------------------------------------------
// k1: pa = x@Wa^T, pbb = x@Wb^T + b1 from W1T (coalesced). 256 blk x 256 thr.
// ---------------------------------------------------------------------------
__global__ __launch_bounds__(256) void k1_papb(const float* __restrict__ x,
                                               const float* __restrict__ W1T,
                                               const float* __restrict__ b1,
                                               float* __restrict__ pa,
                                               float* __restrict__ pbb) {
    __shared__ float xs[2][DD];
    const int b = blockIdx.x;
    const int t = threadIdx.x;
    const int i0 = b * 2;
    if (t < 64) {
        const int f = t * 4;
        *(float4*)&xs[f >> 7][f & 127] = *(const float4*)&x[i0 * DD + f];
    }
    __syncthreads();
    const float* wt = W1T + t;
    const int crot = (b * 8) & 127;
    float pe0 = 0.f, po0 = 0.f, pe1 = 0.f, po1 = 0.f;
    float qe0 = 0.f, qo0 = 0.f, qe1 = 0.f, qo1 = 0.f;
    #pragma unroll 2
    for (int cc0 = 0; cc0 < 128; cc0 += 8) {
        const int c = (cc0 + crot) & 127;
        float w0 = wt[(c + 0) * HH], w1 = wt[(c + 1) * HH];
        float w2 = wt[(c + 2) * HH], w3 = wt[(c + 3) * HH];
        float w4 = wt[(c + 4) * HH], w5 = wt[(c + 5) * HH];
        float w6 = wt[(c + 6) * HH], w7 = wt[(c + 7) * HH];
        float v0 = wt[(128 + c + 0) * HH], v1 = wt[(128 + c + 1) * HH];
        float v2 = wt[(128 + c + 2) * HH], v3 = wt[(128 + c + 3) * HH];
        float v4 = wt[(128 + c + 4) * HH], v5 = wt[(128 + c + 5) * HH];
        float v6 = wt[(128 + c + 6) * HH], v7 = wt[(128 + c + 7) * HH];
        float4 x0a = *(const float4*)&xs[0][c];
        float4 x0b = *(const float4*)&xs[0][c + 4];
        float4 x1a = *(const float4*)&xs[1][c];
        float4 x1b = *(const float4*)&xs[1][c + 4];
        pe0 += w0 * x0a.x + w1 * x0a.y + w2 * x0a.z + w3 * x0a.w;
        po0 += w4 * x0b.x + w5 * x0b.y + w6 * x0b.z + w7 * x0b.w;
        pe1 += w0 * x1a.x + w1 * x1a.y + w2 * x1a.z + w3 * x1a.w;
        po1 += w4 * x1b.x + w5 * x1b.y + w6 * x1b.z + w7 * x1b.w;
        qe0 += v0 * x0a.x + v1 * x0a.y + v2 * x0a.z + v3 * x0a.w;
        qo0 += v4 * x0b.x + v5 * x0b.y + v6 * x0b.z + v7 * x0b.w;
        qe1 += v0 * x1a.x + v1 * x1a.y + v2 * x1a.z + v3 * x1a.w;
        qo1 += v4 * x1b.x + v5 * x1b.y + v6 * x1b.z + v7 * x1b.w;
    }
    const float bb = b1[t];
    pa[i0 * HH + t] = pe0 + po0;
    pa[(i0 + 1) * HH + t] = pe1 + po1;
    pbb[i0 * HH + t] = qe0 + qo0 + bb;
    pbb[(i0 + 1) * HH + t] = qe1 + qo1 + bb;
}

// ---------------------------------------------------------------------------
// k2: T + rowsum + 3 stage GEMMs. 256 blocks x 1024 threads, 2 rows/block.
// Rotated streams (R8) + parallel reduces (R10's one good change).
// ---------------------------------------------------------------------------
__device__ __forceinline__ void stage_dot8(const float* __restrict__ wt,
                                           const float* in0, const float* in1,
                                           int hrot, float& A0, float& A1) {
    float e0 = 0.f, o0 = 0.f, e1 = 0.f, o1 = 0.f;
    #pragma unroll 2
    for (int hh0 = 0; hh0 < 64; hh0 += 8) {
        const int hh = (hh0 + hrot) & 63;
        float w0 = wt[(hh + 0) * HH], w1 = wt[(hh + 1) * HH];
        float w2 = wt[(hh + 2) * HH], w3 = wt[(hh + 3) * HH];
        float w4 = wt[(hh + 4) * HH], w5 = wt[(hh + 5) * HH];
        float w6 = wt[(hh + 6) * HH], w7 = wt[(hh + 7) * HH];
        float4 t0a = *(const float4*)&in0[hh];
        float4 t0b = *(const float4*)&in0[hh + 4];
        float4 t1a = *(const float4*)&in1[hh];
        float4 t1b = *(const float4*)&in1[hh + 4];
        e0 += w0 * t0a.x + w1 * t0a.y + w2 * t0a.z + w3 * t0a.w;
        o0 += w4 * t0b.x + w5 * t0b.y + w6 * t0b.z + w7 * t0b.w;
        e1 += w0 * t1a.x + w1 * t1a.y + w2 * t1a.z + w3 * t1a.w;
        o1 += w4 * t1b.x + w5 * t1b.y + w6 * t1b.z + w7 * t1b.w;
    }
    A0 = e0 + o0;
    A1 = e1 + o1;
}

__global__ __launch_bounds__(1024) void k2_rest(const float* __restrict__ adj,
                                                const float* __restrict__ pa,
                                                const float* __restrict__ pbb,
                                                const float* __restrict__ wsT,
                                                const float* __restrict__ b2,
                                                const float* __restrict__ bo1,
                                                const float* __restrict__ bo2,
                                                float* __restrict__ out) {
    __shared__ float adjs[2][NN];
    __shared__ float pbbs[2][HH];
    __shared__ float ts[2][HH];
    __shared__ float buf1[2][HH];
    __shared__ float buf2[2][HH];
    __shared__ float redbuf[2048];
    __shared__ float rsum_s[2];

    const int b = blockIdx.x;
    const int t = threadIdx.x;
    const int i0 = b * 2;

    if (t < 256) {
        const int f = t * 4;
        *(float4*)&adjs[f >> 9][f & 511] = *(const float4*)&adj[(i0 + (f >> 9)) * NN + (f & 511)];
    } else if (t < 384) {
        const int f = (t - 256) * 4;
        *(float4*)&pbbs[f >> 8][f & 255] = *(const float4*)&pbb[(i0 + (f >> 8)) * HH + (f & 255)];
    }
    __syncthreads();

    if (t < 128) {
        const int r = t >> 6, l = t & 63;
        float s = 0.f;
        #pragma unroll
        for (int m = 0; m < 8; ++m) s += adjs[r][l + 64 * m];
        #pragma unroll
        for (int off = 32; off > 0; off >>= 1) s += __shfl_down(s, off, 64);
        if (l == 0) rsum_s[r] = s;
    }

    // ---- T phase: hb = t>>9, jq = (t>>7)&3, hl = t&127, rotated j stream ----
    {
        const int hb = t >> 9;
        const int jq = (t >> 7) & 3;
        const int hl = t & 127;
        const int h = hb * 128 + hl;
        const float pb0 = pbbs[0][h];
        const float pb1 = pbbs[1][h];
        const float* pac = pa + (jq * 128) * HH + h;
        const float* arow0 = &adjs[0][jq * 128];
        const float* arow1 = &adjs[1][jq * 128];
        const int jrot = (b * 8) & 127;
        float ae0 = 0.f, ao0 = 0.f, ae1 = 0.f, ao1 = 0.f;
        #pragma unroll 2
        for (int jj0 = 0; jj0 < 128; jj0 += 8) {
            const int j = (jj0 + jrot) & 127;
            float p0 = pac[(j + 0) * HH], p1 = pac[(j + 1) * HH];
            float p2 = pac[(j + 2) * HH], p3 = pac[(j + 3) * HH];
            float p4 = pac[(j + 4) * HH], p5 = pac[(j + 5) * HH];
            float p6 = pac[(j + 6) * HH], p7 = pac[(j + 7) * HH];
            float4 A0a = *(const float4*)&arow0[j];
            float4 A0b = *(const float4*)&arow0[j + 4];
            float4 A1a = *(const float4*)&arow1[j];
            float4 A1b = *(const float4*)&arow1[j + 4];
            float r0 = fmaxf(p0 + pb0, 0.f), r1 = fmaxf(p1 + pb0, 0.f);
            float r2 = fmaxf(p2 + pb0, 0.f), r3 = fmaxf(p3 + pb0, 0.f);
            float r4 = fmaxf(p4 + pb0, 0.f), r5 = fmaxf(p5 + pb0, 0.f);
            float r6 = fmaxf(p6 + pb0, 0.f), r7 = fmaxf(p7 + pb0, 0.f);
            ae0 += A0a.x * r0 + A0a.y * r1 + A0a.z * r2 + A0a.w * r3;
            ao0 += A0b.x * r4 + A0b.y * r5 + A0b.z * r6 + A0b.w * r7;
            float s0 = fmaxf(p0 + pb1, 0.f), s1 = fmaxf(p1 + pb1, 0.f);
            float s2 = fmaxf(p2 + pb1, 0.f), s3 = fmaxf(p3 + pb1, 0.f);
            float s4 = fmaxf(p4 + pb1, 0.f), s5 = fmaxf(p5 + pb1, 0.f);
            float s6 = fmaxf(p6 + pb1, 0.f), s7 = fmaxf(p7 + pb1, 0.f);
            ae1 += A1a.x * s0 + A1a.y * s1 + A1a.z * s2 + A1a.w * s3;
            ao1 += A1b.x * s4 + A1b.y * s5 + A1b.z * s6 + A1b.w * s7;
        }
        redbuf[((jq * 2 + hb) * 2 + 0) * 128 + hl] = ae0 + ao0;
        redbuf[((jq * 2 + hb) * 2 + 1) * 128 + hl] = ae1 + ao1;
        __syncthreads();
        if (jq < 2) {
            const int r = jq;
            float s = 0.f;
            #pragma unroll
            for (int q = 0; q < 4; ++q)
                s += redbuf[((q * 2 + hb) * 2 + r) * 128 + hl];
            ts[r][h] = s;
        }
    }
    __syncthreads();

    const int k = t & 255;
    const int hp = t >> 8;
    const int hrot = (b * 8) & 63;
    const float* W2T  = wsT + 1 * (HH * HH);
    const float* Wo1T = wsT + 2 * (HH * HH);
    const float* Wo2T = wsT + 3 * (HH * HH);

    // stage 1: pred = (ts @ W2T + b2*rowsum)/N -> buf1
    {
        float a0, a1;
        stage_dot8(W2T + (hp * 64) * HH + k, &ts[0][hp * 64], &ts[1][hp * 64], hrot, a0, a1);
        redbuf[(hp * 2 + 0) * 256 + k] = a0;
        redbuf[(hp * 2 + 1) * 256 + k] = a1;
        __syncthreads();
        if (hp < 2) {
            const int r = hp;
            float s = 0.f;
            #pragma unroll
            for (int p = 0; p < 4; ++p) s += redbuf[(p * 2 + r) * 256 + k];
            buf1[r][k] = (s + b2[k] * rsum_s[r]) * (1.0f / (float)NN);
        }
    }
    __syncthreads();

    // stage 2: h2 = relu(pred @ Wo1T + bo1) -> buf2
    {
        float a0, a1;
        stage_dot8(Wo1T + (hp * 64) * HH + k, &buf1[0][hp * 64], &buf1[1][hp * 64], hrot, a0, a1);
        redbuf[(hp * 2 + 0) * 256 + k] = a0;
        redbuf[(hp * 2 + 1) * 256 + k] = a1;
        __syncthreads();
        if (hp < 2) {
            const int r = hp;
            float s = 0.f;
            #pragma unroll
            for (int p = 0; p < 4; ++p) s += redbuf[(p * 2 + r) * 256 + k];
            buf2[r][k] = fmaxf(s + bo1[k], 0.f);
        }
    }
    __syncthreads();

    // stage 3: out = h2 @ Wo2T + bo2
    {
        float a0, a1;
        stage_dot8(Wo2T + (hp * 64) * HH + k, &buf2[0][hp * 64], &buf2[1][hp * 64], hrot, a0, a1);
        redbuf[(hp * 2 + 0) * 256 + k] = a0;
        redbuf[(hp * 2 + 1) * 256 + k] = a1;
        __syncthreads();
        if (hp < 2) {
            const int r = hp;
            float s = 0.f;
            #pragma unroll
            for (int p = 0; p < 4; ++p) s += redbuf[(p * 2 + r) * 256 + k];
            out[(i0 + r) * HH + k] = s + bo2[k];
        }
    }
}

extern "C" void kernel_launch(void* const* d_in, const int* in_sizes, int n_in,
                              void* d_out, int out_size, void* d_ws, size_t ws_size,
                              hipStream_t stream) {
    const float* x   = (const float*)d_in[0];
    const float* adj = (const float*)d_in[1];
    const float* W1  = (const float*)d_in[2];
    const float* b1  = (const float*)d_in[3];
    const float* W2  = (const float*)d_in[4];
    const float* b2  = (const float*)d_in[5];
    const float* Wo1 = (const float*)d_in[6];
    const float* bo1 = (const float*)d_in[7];
    const float* Wo2 = (const float*)d_in[8];
    const float* bo2 = (const float*)d_in[9];
    float* out = (float*)d_out;
    float* ws  = (float*)d_ws;

    float* wsT = ws;            // 4 * 65536: W1T, W2T, Wo1T, Wo2T
    float* pa  = ws + 262144;   // 131072
    float* pbb = ws + 393216;   // 131072

    k0_tr<<<64, 256, 0, stream>>>(W1, W2, Wo1, Wo2, wsT);
    k1_papb<<<256, 256, 0, stream>>>(x, wsT, b1, pa, pbb);
    k2_rest<<<256, 1024, 0, stream>>>(adj, pa, pbb, wsT, b2, bo1, bo2, out);
}

// Round 12
// 30.941 us; speedup vs baseline: 1.3205x; 1.0605x over previous
//
#include <hip/hip_runtime.h>

#define NN 512
#define DD 128
#define HH 256

// ---------------------------------------------------------------------------
// k0: transpose W1, W2, Wo1, Wo2 (each 256x256) into ws. 64 blocks x 256 thr.
// ---------------------------------------------------------------------------
__global__ __launch_bounds__(256) void k0_tr(const float* __restrict__ W1,
                                             const float* __restrict__ W2,
                                             const float* __restrict__ Wo1,
                                             const float* __restrict__ Wo2,
                                             float* __restrict__ wsT) {
    __shared__ float tl[64][68];
    const int b = blockIdx.x;
    const int t = threadIdx.x;
    const int m = b >> 4, tile = b & 15;
    const float* src = (m == 0) ? W1 : (m == 1) ? W2 : (m == 2) ? Wo1 : Wo2;
    float* dst = wsT + m * (HH * HH);
    const int sr0 = (tile >> 2) * 64;
    const int sc0 = (tile & 3) * 64;
    const int rr = t >> 4;
    const int cc = (t & 15) * 4;
    #pragma unroll
    for (int it = 0; it < 4; ++it) {
        const int row = rr + 16 * it;
        float4 v = *(const float4*)&src[(sr0 + row) * HH + sc0 + cc];
        tl[row][cc + 0] = v.x;
        tl[row][cc + 1] = v.y;
        tl[row][cc + 2] = v.z;
        tl[row][cc + 3] = v.w;
    }
    __syncthreads();
    #pragma unroll
    for (int it = 0; it < 4; ++it) {
        const int lc = rr + 16 * it;
        float4 o;
        o.x = tl[cc + 0][lc];
        o.y = tl[cc + 1][lc];
        o.z = tl[cc + 2][lc];
        o.w = tl[cc + 3][lc];
        *(float4*)&dst[(sc0 + lc) * HH + sr0 + cc] = o;
    }
}

// ---------------------------------------------------------------------------
// k1: pa = x@Wa^T, pbb = x@Wb^T + b1 from W1T (coalesced). 256 blk x 256 thr.
// ---------------------------------------------------------------------------
__global__ __launch_bounds__(256) void k1_papb(const float* __restrict__ x,
                                               const float* __restrict__ W1T,
                                               const float* __restrict__ b1,
                                               float* __restrict__ pa,
                                               float* __restrict__ pbb) {
    __shared__ float xs[2][DD];
    const int b = blockIdx.x;
    const int t = threadIdx.x;
    const int i0 = b * 2;
    if (t < 64) {
        const int f = t * 4;
        *(float4*)&xs[f >> 7][f & 127] = *(const float4*)&x[i0 * DD + f];
    }
    __syncthreads();
    const float* wt = W1T + t;
    const int crot = (b * 8) & 127;
    float pe0 = 0.f, po0 = 0.f, pe1 = 0.f, po1 = 0.f;
    float qe0 = 0.f, qo0 = 0.f, qe1 = 0.f, qo1 = 0.f;
    #pragma unroll 2
    for (int cc0 = 0; cc0 < 128; cc0 += 8) {
        const int c = (cc0 + crot) & 127;
        float w0 = wt[(c + 0) * HH], w1 = wt[(c + 1) * HH];
        float w2 = wt[(c + 2) * HH], w3 = wt[(c + 3) * HH];
        float w4 = wt[(c + 4) * HH], w5 = wt[(c + 5) * HH];
        float w6 = wt[(c + 6) * HH], w7 = wt[(c + 7) * HH];
        float v0 = wt[(128 + c + 0) * HH], v1 = wt[(128 + c + 1) * HH];
        float v2 = wt[(128 + c + 2) * HH], v3 = wt[(128 + c + 3) * HH];
        float v4 = wt[(128 + c + 4) * HH], v5 = wt[(128 + c + 5) * HH];
        float v6 = wt[(128 + c + 6) * HH], v7 = wt[(128 + c + 7) * HH];
        float4 x0a = *(const float4*)&xs[0][c];
        float4 x0b = *(const float4*)&xs[0][c + 4];
        float4 x1a = *(const float4*)&xs[1][c];
        float4 x1b = *(const float4*)&xs[1][c + 4];
        pe0 += w0 * x0a.x + w1 * x0a.y + w2 * x0a.z + w3 * x0a.w;
        po0 += w4 * x0b.x + w5 * x0b.y + w6 * x0b.z + w7 * x0b.w;
        pe1 += w0 * x1a.x + w1 * x1a.y + w2 * x1a.z + w3 * x1a.w;
        po1 += w4 * x1b.x + w5 * x1b.y + w6 * x1b.z + w7 * x1b.w;
        qe0 += v0 * x0a.x + v1 * x0a.y + v2 * x0a.z + v3 * x0a.w;
        qo0 += v4 * x0b.x + v5 * x0b.y + v6 * x0b.z + v7 * x0b.w;
        qe1 += v0 * x1a.x + v1 * x1a.y + v2 * x1a.z + v3 * x1a.w;
        qo1 += v4 * x1b.x + v5 * x1b.y + v6 * x1b.z + v7 * x1b.w;
    }
    const float bb = b1[t];
    pa[i0 * HH + t] = pe0 + po0;
    pa[(i0 + 1) * HH + t] = pe1 + po1;
    pbb[i0 * HH + t] = qe0 + qo0 + bb;
    pbb[(i0 + 1) * HH + t] = qe1 + qo1 + bb;
}

// ---------------------------------------------------------------------------
// k2: all global streams float4-vectorized. 256 blocks x 1024 threads.
// T phase : hq = t&63 (h-quad), js = t>>6 (16-way j split), float4 pa loads.
// Stages  : kq = t&63 (k-quad), hp = t>>6 (16-way h split), float4 WT loads.
// ---------------------------------------------------------------------------
__global__ __launch_bounds__(1024) void k2_rest(const float* __restrict__ adj,
                                                const float* __restrict__ pa,
                                                const float* __restrict__ pbb,
                                                const float* __restrict__ wsT,
                                                const float* __restrict__ b2,
                                                const float* __restrict__ bo1,
                                                const float* __restrict__ bo2,
                                                float* __restrict__ out) {
    __shared__ float adjs[2][NN];          // 4 KB
    __shared__ float4 pbbs4[2][64];        // 2 KB
    __shared__ float ts[2][HH];            // 2 KB
    __shared__ float buf1[2][HH];          // 2 KB
    __shared__ float buf2[2][HH];          // 2 KB
    __shared__ float redbuf[8192];         // 32 KB
    __shared__ float rsum_s[2];

    const int b = blockIdx.x;
    const int t = threadIdx.x;
    const int i0 = b * 2;

    if (t < 256) {
        const int f = t * 4;
        *(float4*)&adjs[f >> 9][f & 511] = *(const float4*)&adj[(i0 + (f >> 9)) * NN + (f & 511)];
    } else if (t < 384) {
        const int u = t - 256;                 // 0..127: (row, hq)
        const int r = u >> 6, q = u & 63;
        pbbs4[r][q] = *(const float4*)&pbb[(i0 + r) * HH + q * 4];
    }
    __syncthreads();

    if (t < 128) {
        const int r = t >> 6, l = t & 63;
        float s = 0.f;
        #pragma unroll
        for (int m = 0; m < 8; ++m) s += adjs[r][l + 64 * m];
        #pragma unroll
        for (int off = 32; off > 0; off >>= 1) s += __shfl_down(s, off, 64);
        if (l == 0) rsum_s[r] = s;
    }

    // ---- T phase ----
    {
        const int hq = t & 63;
        const int js = t >> 6;             // 0..15, 32 j each
        const float4 pb0 = pbbs4[0][hq];
        const float4 pb1 = pbbs4[1][hq];
        float4 ac0 = {0.f, 0.f, 0.f, 0.f};
        float4 ac1 = {0.f, 0.f, 0.f, 0.f};
        #pragma unroll 4
        for (int jj = 0; jj < 32; ++jj) {
            const int j = js * 32 + ((jj + b) & 31);
            float4 p = *(const float4*)&pa[j * HH + hq * 4];
            const float a0 = adjs[0][j];
            const float a1 = adjs[1][j];
            float4 q0, q1;
            q0.x = fmaxf(p.x + pb0.x, 0.f); q0.y = fmaxf(p.y + pb0.y, 0.f);
            q0.z = fmaxf(p.z + pb0.z, 0.f); q0.w = fmaxf(p.w + pb0.w, 0.f);
            q1.x = fmaxf(p.x + pb1.x, 0.f); q1.y = fmaxf(p.y + pb1.y, 0.f);
            q1.z = fmaxf(p.z + pb1.z, 0.f); q1.w = fmaxf(p.w + pb1.w, 0.f);
            ac0.x += a0 * q0.x; ac0.y += a0 * q0.y;
            ac0.z += a0 * q0.z; ac0.w += a0 * q0.w;
            ac1.x += a1 * q1.x; ac1.y += a1 * q1.y;
            ac1.z += a1 * q1.z; ac1.w += a1 * q1.w;
        }
        *(float4*)&redbuf[(js * 2 + 0) * 256 + hq * 4] = ac0;
        *(float4*)&redbuf[(js * 2 + 1) * 256 + hq * 4] = ac1;
        __syncthreads();
        if (t < 512) {
            const int r = t >> 8, h = t & 255;
            float s = 0.f;
            #pragma unroll
            for (int q = 0; q < 16; ++q) s += redbuf[(q * 2 + r) * 256 + h];
            ts[r][h] = s;
        }
    }
    __syncthreads();

    const int kq = t & 63;
    const int hp = t >> 6;                 // 0..15, 16 h each
    const float* W2T  = wsT + 1 * (HH * HH);
    const float* Wo1T = wsT + 2 * (HH * HH);
    const float* Wo2T = wsT + 3 * (HH * HH);

    // stage 1: pred = (ts @ W2T + b2*rowsum)/N -> buf1
    {
        float4 a0 = {0.f, 0.f, 0.f, 0.f};
        float4 a1 = {0.f, 0.f, 0.f, 0.f};
        #pragma unroll 4
        for (int hh = 0; hh < 16; ++hh) {
            const int h = hp * 16 + hh;
            float4 w = *(const float4*)&W2T[h * HH + kq * 4];
            const float v0 = ts[0][h];
            const float v1 = ts[1][h];
            a0.x += w.x * v0; a0.y += w.y * v0; a0.z += w.z * v0; a0.w += w.w * v0;
            a1.x += w.x * v1; a1.y += w.y * v1; a1.z += w.z * v1; a1.w += w.w * v1;
        }
        *(float4*)&redbuf[(hp * 2 + 0) * 256 + kq * 4] = a0;
        *(float4*)&redbuf[(hp * 2 + 1) * 256 + kq * 4] = a1;
        __syncthreads();
        if (t < 512) {
            const int r = t >> 8, k = t & 255;
            float s = 0.f;
            #pragma unroll
            for (int p = 0; p < 16; ++p) s += redbuf[(p * 2 + r) * 256 + k];
            buf1[r][k] = (s + b2[k] * rsum_s[r]) * (1.0f / (float)NN);
        }
    }
    __syncthreads();

    // stage 2: h2 = relu(pred @ Wo1T + bo1) -> buf2
    {
        float4 a0 = {0.f, 0.f, 0.f, 0.f};
        float4 a1 = {0.f, 0.f, 0.f, 0.f};
        #pragma unroll 4
        for (int hh = 0; hh < 16; ++hh) {
            const int h = hp * 16 + hh;
            float4 w = *(const float4*)&Wo1T[h * HH + kq * 4];
            const float v0 = buf1[0][h];
            const float v1 = buf1[1][h];
            a0.x += w.x * v0; a0.y += w.y * v0; a0.z += w.z * v0; a0.w += w.w * v0;
            a1.x += w.x * v1; a1.y += w.y * v1; a1.z += w.z * v1; a1.w += w.w * v1;
        }
        *(float4*)&redbuf[(hp * 2 + 0) * 256 + kq * 4] = a0;
        *(float4*)&redbuf[(hp * 2 + 1) * 256 + kq * 4] = a1;
        __syncthreads();
        if (t < 512) {
            const int r = t >> 8, k = t & 255;
            float s = 0.f;
            #pragma unroll
            for (int p = 0; p < 16; ++p) s += redbuf[(p * 2 + r) * 256 + k];
            buf2[r][k] = fmaxf(s + bo1[k], 0.f);
        }
    }
    __syncthreads();

    // stage 3: out = h2 @ Wo2T + bo2
    {
        float4 a0 = {0.f, 0.f, 0.f, 0.f};
        float4 a1 = {0.f, 0.f, 0.f, 0.f};
        #pragma unroll 4
        for (int hh = 0; hh < 16; ++hh) {
            const int h = hp * 16 + hh;
            float4 w = *(const float4*)&Wo2T[h * HH + kq * 4];
            const float v0 = buf2[0][h];
            const float v1 = buf2[1][h];
            a0.x += w.x * v0; a0.y += w.y * v0; a0.z += w.z * v0; a0.w += w.w * v0;
            a1.x += w.x * v1; a1.y += w.y * v1; a1.z += w.z * v1; a1.w += w.w * v1;
        }
        *(float4*)&redbuf[(hp * 2 + 0) * 256 + kq * 4] = a0;
        *(float4*)&redbuf[(hp * 2 + 1) * 256 + kq * 4] = a1;
        __syncthreads();
        if (t < 512) {
            const int r = t >> 8, k = t & 255;
            float s = 0.f;
            #pragma unroll
            for (int p = 0; p < 16; ++p) s += redbuf[(p * 2 + r) * 256 + k];
            out[(i0 + r) * HH + k] = s + bo2[k];
        }
    }
}

extern "C" void kernel_launch(void* const* d_in, const int* in_sizes, int n_in,
                              void* d_out, int out_size, void* d_ws, size_t ws_size,
                              hipStream_t stream) {
    const float* x   = (const float*)d_in[0];
    const float* adj = (const float*)d_in[1];
    const float* W1  = (const float*)d_in[2];
    const float* b1  = (const float*)d_in[3];
    const float* W2  = (const float*)d_in[4];
    const float* b2  = (const float*)d_in[5];
    const float* Wo1 = (const float*)d_in[6];
    const float* bo1 = (const float*)d_in[7];
    const float* Wo2 = (const float*)d_in[8];
    const float* bo2 = (const float*)d_in[9];
    float* out = (float*)d_out;
    float* ws  = (float*)d_ws;

    float* wsT = ws;            // 4 * 65536: W1T, W2T, Wo1T, Wo2T
    float* pa  = ws + 262144;   // 131072
    float* pbb = ws + 393216;   // 131072

    k0_tr<<<64, 256, 0, stream>>>(W1, W2, Wo1, Wo2, wsT);
    k1_papb<<<256, 256, 0, stream>>>(x, wsT, b1, pa, pbb);
    k2_rest<<<256, 1024, 0, stream>>>(adj, pa, pbb, wsT, b2, bo1, bo2, out);
}

// Round 14
// 30.351 us; speedup vs baseline: 1.3461x; 1.0194x over previous
//
#include <hip/hip_runtime.h>

#define NN 512
#define DD 128
#define HH 256

typedef unsigned int uint32;
typedef unsigned short u16;

__device__ __forceinline__ uint32 bfr(float f) {
    uint32 u = __float_as_uint(f);
    return (u + 0x7fffu + ((u >> 16) & 1u)) >> 16;   // RNE bf16
}

// ---------------------------------------------------------------------------
// k0: W1 -> W1T (f32, for k1); W2/Wo1/Wo2 -> transposed bf16 (for k2).
// 64 blocks x 256 threads.
// ---------------------------------------------------------------------------
__global__ __launch_bounds__(256) void k0_tr(const float* __restrict__ W1,
                                             const float* __restrict__ W2,
                                             const float* __restrict__ Wo1,
                                             const float* __restrict__ Wo2,
                                             float* __restrict__ W1T,
                                             u16* __restrict__ wTb) {
    __shared__ float tl[64][68];
    const int b = blockIdx.x;
    const int t = threadIdx.x;
    const int m = b >> 4, tile = b & 15;
    const float* src = (m == 0) ? W1 : (m == 1) ? W2 : (m == 2) ? Wo1 : Wo2;
    const int sr0 = (tile >> 2) * 64;
    const int sc0 = (tile & 3) * 64;
    const int rr = t >> 4;
    const int cc = (t & 15) * 4;
    #pragma unroll
    for (int it = 0; it < 4; ++it) {
        const int row = rr + 16 * it;
        float4 v = *(const float4*)&src[(sr0 + row) * HH + sc0 + cc];
        tl[row][cc + 0] = v.x;
        tl[row][cc + 1] = v.y;
        tl[row][cc + 2] = v.z;
        tl[row][cc + 3] = v.w;
    }
    __syncthreads();
    if (m == 0) {
        #pragma unroll
        for (int it = 0; it < 4; ++it) {
            const int lc = rr + 16 * it;
            float4 o;
            o.x = tl[cc + 0][lc];
            o.y = tl[cc + 1][lc];
            o.z = tl[cc + 2][lc];
            o.w = tl[cc + 3][lc];
            *(float4*)&W1T[(sc0 + lc) * HH + sr0 + cc] = o;
        }
    } else {
        u16* dst = wTb + (m - 1) * (HH * HH);
        #pragma unroll
        for (int it = 0; it < 4; ++it) {
            const int lc = rr + 16 * it;
            uint32 lo = bfr(tl[cc + 0][lc]) | (bfr(tl[cc + 1][lc]) << 16);
            uint32 hi = bfr(tl[cc + 2][lc]) | (bfr(tl[cc + 3][lc]) << 16);
            uint32* p = (uint32*)&dst[(sc0 + lc) * HH + sr0 + cc];
            p[0] = lo;
            p[1] = hi;
        }
    }
}

// ---------------------------------------------------------------------------
// k1: pa = x@Wa^T, pbb = x@Wb^T + b1 from W1T (f32, verbatim from R12).
// ---------------------------------------------------------------------------
__global__ __launch_bounds__(256) void k1_papb(const float* __restrict__ x,
                                               const float* __restrict__ W1T,
                                               const float* __restrict__ b1,
                                               float* __restrict__ pa,
                                               float* __restrict__ pbb) {
    __shared__ float xs[2][DD];
    const int b = blockIdx.x;
    const int t = threadIdx.x;
    const int i0 = b * 2;
    if (t < 64) {
        const int f = t * 4;
        *(float4*)&xs[f >> 7][f & 127] = *(const float4*)&x[i0 * DD + f];
    }
    __syncthreads();
    const float* wt = W1T + t;
    const int crot = (b * 8) & 127;
    float pe0 = 0.f, po0 = 0.f, pe1 = 0.f, po1 = 0.f;
    float qe0 = 0.f, qo0 = 0.f, qe1 = 0.f, qo1 = 0.f;
    #pragma unroll 2
    for (int cc0 = 0; cc0 < 128; cc0 += 8) {
        const int c = (cc0 + crot) & 127;
        float w0 = wt[(c + 0) * HH], w1 = wt[(c + 1) * HH];
        float w2 = wt[(c + 2) * HH], w3 = wt[(c + 3) * HH];
        float w4 = wt[(c + 4) * HH], w5 = wt[(c + 5) * HH];
        float w6 = wt[(c + 6) * HH], w7 = wt[(c + 7) * HH];
        float v0 = wt[(128 + c + 0) * HH], v1 = wt[(128 + c + 1) * HH];
        float v2 = wt[(128 + c + 2) * HH], v3 = wt[(128 + c + 3) * HH];
        float v4 = wt[(128 + c + 4) * HH], v5 = wt[(128 + c + 5) * HH];
        float v6 = wt[(128 + c + 6) * HH], v7 = wt[(128 + c + 7) * HH];
        float4 x0a = *(const float4*)&xs[0][c];
        float4 x0b = *(const float4*)&xs[0][c + 4];
        float4 x1a = *(const float4*)&xs[1][c];
        float4 x1b = *(const float4*)&xs[1][c + 4];
        pe0 += w0 * x0a.x + w1 * x0a.y + w2 * x0a.z + w3 * x0a.w;
        po0 += w4 * x0b.x + w5 * x0b.y + w6 * x0b.z + w7 * x0b.w;
        pe1 += w0 * x1a.x + w1 * x1a.y + w2 * x1a.z + w3 * x1a.w;
        po1 += w4 * x1b.x + w5 * x1b.y + w6 * x1b.z + w7 * x1b.w;
        qe0 += v0 * x0a.x + v1 * x0a.y + v2 * x0a.z + v3 * x0a.w;
        qo0 += v4 * x0b.x + v5 * x0b.y + v6 * x0b.z + v7 * x0b.w;
        qe1 += v0 * x1a.x + v1 * x1a.y + v2 * x1a.z + v3 * x1a.w;
        qo1 += v4 * x1b.x + v5 * x1b.y + v6 * x1b.z + v7 * x1b.w;
    }
    const float bb = b1[t];
    pa[i0 * HH + t] = pe0 + po0;
    pa[(i0 + 1) * HH + t] = pe1 + po1;
    pbb[i0 * HH + t] = qe0 + qo0 + bb;
    pbb[(i0 + 1) * HH + t] = qe1 + qo1 + bb;
}

// ---------------------------------------------------------------------------
// k2: R12 structure; stage weights decoded from bf16. 256 blk x 1024 thr.
// ---------------------------------------------------------------------------
__global__ __launch_bounds__(1024) void k2_rest(const float* __restrict__ adj,
                                                const float* __restrict__ pa,
                                                const float* __restrict__ pbb,
                                                const u16* __restrict__ wTb,
                                                const float* __restrict__ b2,
                                                const float* __restrict__ bo1,
                                                const float* __restrict__ bo2,
                                                float* __restrict__ out) {
    __shared__ float adjs[2][NN];
    __shared__ float4 pbbs4[2][64];
    __shared__ float ts[2][HH];
    __shared__ float buf1[2][HH];
    __shared__ float buf2[2][HH];
    __shared__ float redbuf[8192];
    __shared__ float rsum_s[2];

    const int b = blockIdx.x;
    const int t = threadIdx.x;
    const int i0 = b * 2;

    if (t < 256) {
        const int f = t * 4;
        *(float4*)&adjs[f >> 9][f & 511] = *(const float4*)&adj[(i0 + (f >> 9)) * NN + (f & 511)];
    } else if (t < 384) {
        const int u = t - 256;
        const int r = u >> 6, q = u & 63;
        pbbs4[r][q] = *(const float4*)&pbb[(i0 + r) * HH + q * 4];
    }
    __syncthreads();

    if (t < 128) {
        const int r = t >> 6, l = t & 63;
        float s = 0.f;
        #pragma unroll
        for (int m = 0; m < 8; ++m) s += adjs[r][l + 64 * m];
        #pragma unroll
        for (int off = 32; off > 0; off >>= 1) s += __shfl_down(s, off, 64);
        if (l == 0) rsum_s[r] = s;
    }

    // ---- T phase (f32 pa, float4 loads; verbatim R12) ----
    {
        const int hq = t & 63;
        const int js = t >> 6;
        const float4 pb0 = pbbs4[0][hq];
        const float4 pb1 = pbbs4[1][hq];
        float4 ac0 = {0.f, 0.f, 0.f, 0.f};
        float4 ac1 = {0.f, 0.f, 0.f, 0.f};
        #pragma unroll 4
        for (int jj = 0; jj < 32; ++jj) {
            const int j = js * 32 + ((jj + b) & 31);
            float4 p = *(const float4*)&pa[j * HH + hq * 4];
            const float a0 = adjs[0][j];
            const float a1 = adjs[1][j];
            ac0.x += a0 * fmaxf(p.x + pb0.x, 0.f);
            ac0.y += a0 * fmaxf(p.y + pb0.y, 0.f);
            ac0.z += a0 * fmaxf(p.z + pb0.z, 0.f);
            ac0.w += a0 * fmaxf(p.w + pb0.w, 0.f);
            ac1.x += a1 * fmaxf(p.x + pb1.x, 0.f);
            ac1.y += a1 * fmaxf(p.y + pb1.y, 0.f);
            ac1.z += a1 * fmaxf(p.z + pb1.z, 0.f);
            ac1.w += a1 * fmaxf(p.w + pb1.w, 0.f);
        }
        *(float4*)&redbuf[(js * 2 + 0) * 256 + hq * 4] = ac0;
        *(float4*)&redbuf[(js * 2 + 1) * 256 + hq * 4] = ac1;
        __syncthreads();
        if (t < 512) {
            const int r = t >> 8, h = t & 255;
            float s = 0.f;
            #pragma unroll
            for (int q = 0; q < 16; ++q) s += redbuf[(q * 2 + r) * 256 + h];
            ts[r][h] = s;
        }
    }
    __syncthreads();

    const int kq = t & 63;
    const int hp = t >> 6;
    const uint32* W2U  = (const uint32*)wTb;
    const uint32* Wo1U = W2U + (HH * HH) / 2;
    const uint32* Wo2U = W2U + (HH * HH);

    // stage 1: pred = (ts @ W2T + b2*rowsum)/N -> buf1
    {
        float4 a0 = {0.f, 0.f, 0.f, 0.f};
        float4 a1 = {0.f, 0.f, 0.f, 0.f};
        #pragma unroll 4
        for (int hh = 0; hh < 16; ++hh) {
            const int h = hp * 16 + hh;
            uint32 wx = W2U[h * 128 + kq * 2];
            uint32 wy = W2U[h * 128 + kq * 2 + 1];
            float w0 = __uint_as_float(wx << 16);
            float w1 = __uint_as_float(wx & 0xffff0000u);
            float w2 = __uint_as_float(wy << 16);
            float w3 = __uint_as_float(wy & 0xffff0000u);
            const float v0 = ts[0][h];
            const float v1 = ts[1][h];
            a0.x += w0 * v0; a0.y += w1 * v0; a0.z += w2 * v0; a0.w += w3 * v0;
            a1.x += w0 * v1; a1.y += w1 * v1; a1.z += w2 * v1; a1.w += w3 * v1;
        }
        *(float4*)&redbuf[(hp * 2 + 0) * 256 + kq * 4] = a0;
        *(float4*)&redbuf[(hp * 2 + 1) * 256 + kq * 4] = a1;
        __syncthreads();
        if (t < 512) {
            const int r = t >> 8, k = t & 255;
            float s = 0.f;
            #pragma unroll
            for (int p = 0; p < 16; ++p) s += redbuf[(p * 2 + r) * 256 + k];
            buf1[r][k] = (s + b2[k] * rsum_s[r]) * (1.0f / (float)NN);
        }
    }
    __syncthreads();

    // stage 2: h2 = relu(pred @ Wo1T + bo1) -> buf2
    {
        float4 a0 = {0.f, 0.f, 0.f, 0.f};
        float4 a1 = {0.f, 0.f, 0.f, 0.f};
        #pragma unroll 4
        for (int hh = 0; hh < 16; ++hh) {
            const int h = hp * 16 + hh;
            uint32 wx = Wo1U[h * 128 + kq * 2];
            uint32 wy = Wo1U[h * 128 + kq * 2 + 1];
            float w0 = __uint_as_float(wx << 16);
            float w1 = __uint_as_float(wx & 0xffff0000u);
            float w2 = __uint_as_float(wy << 16);
            float w3 = __uint_as_float(wy & 0xffff0000u);
            const float v0 = buf1[0][h];
            const float v1 = buf1[1][h];
            a0.x += w0 * v0; a0.y += w1 * v0; a0.z += w2 * v0; a0.w += w3 * v0;
            a1.x += w0 * v1; a1.y += w1 * v1; a1.z += w2 * v1; a1.w += w3 * v1;
        }
        *(float4*)&redbuf[(hp * 2 + 0) * 256 + kq * 4] = a0;
        *(float4*)&redbuf[(hp * 2 + 1) * 256 + kq * 4] = a1;
        __syncthreads();
        if (t < 512) {
            const int r = t >> 8, k = t & 255;
            float s = 0.f;
            #pragma unroll
            for (int p = 0; p < 16; ++p) s += redbuf[(p * 2 + r) * 256 + k];
            buf2[r][k] = fmaxf(s + bo1[k], 0.f);
        }
    }
    __syncthreads();

    // stage 3: out = h2 @ Wo2T + bo2
    {
        float4 a0 = {0.f, 0.f, 0.f, 0.f};
        float4 a1 = {0.f, 0.f, 0.f, 0.f};
        #pragma unroll 4
        for (int hh = 0; hh < 16; ++hh) {
            const int h = hp * 16 + hh;
            uint32 wx = Wo2U[h * 128 + kq * 2];
            uint32 wy = Wo2U[h * 128 + kq * 2 + 1];
            float w0 = __uint_as_float(wx << 16);
            float w1 = __uint_as_float(wx & 0xffff0000u);
            float w2 = __uint_as_float(wy << 16);
            float w3 = __uint_as_float(wy & 0xffff0000u);
            const float v0 = buf2[0][h];
            const float v1 = buf2[1][h];
            a0.x += w0 * v0; a0.y += w1 * v0; a0.z += w2 * v0; a0.w += w3 * v0;
            a1.x += w0 * v1; a1.y += w1 * v1; a1.z += w2 * v1; a1.w += w3 * v1;
        }
        *(float4*)&redbuf[(hp * 2 + 0) * 256 + kq * 4] = a0;
        *(float4*)&redbuf[(hp * 2 + 1) * 256 + kq * 4] = a1;
        __syncthreads();
        if (t < 512) {
            const int r = t >> 8, k = t & 255;
            float s = 0.f;
            #pragma unroll
            for (int p = 0; p < 16; ++p) s += redbuf[(p * 2 + r) * 256 + k];
            out[(i0 + r) * HH + k] = s + bo2[k];
        }
    }
}

extern "C" void kernel_launch(void* const* d_in, const int* in_sizes, int n_in,
                              void* d_out, int out_size, void* d_ws, size_t ws_size,
                              hipStream_t stream) {
    const float* x   = (const float*)d_in[0];
    const float* adj = (const float*)d_in[1];
    const float* W1  = (const float*)d_in[2];
    const float* b1  = (const float*)d_in[3];
    const float* W2  = (const float*)d_in[4];
    const float* b2  = (const float*)d_in[5];
    const float* Wo1 = (const float*)d_in[6];
    const float* bo1 = (const float*)d_in[7];
    const float* Wo2 = (const float*)d_in[8];
    const float* bo2 = (const float*)d_in[9];
    float* out = (float*)d_out;
    float* ws  = (float*)d_ws;

    // Disjoint float-slot regions (audited):
    //   W1T : [0,       65536)   f32 256x256
    //   wTb : [65536,  163840)   3 x 256x256 bf16 = 98304 float slots
    //   pa  : [163840, 294912)   f32 512x256
    //   pbb : [294912, 425984)   f32 512x256
    float* W1T = ws;
    u16*   wTb = (u16*)(ws + 65536);
    float* pa  = ws + 163840;
    float* pbb = ws + 294912;

    k0_tr<<<64, 256, 0, stream>>>(W1, W2, Wo1, Wo2, W1T, wTb);
    k1_papb<<<256, 256, 0, stream>>>(x, W1T, b1, pa, pbb);
    k2_rest<<<256, 1024, 0, stream>>>(adj, pa, pbb, wTb, b2, bo1, bo2, out);
}